// Round 1
// baseline (2332.081 us; speedup 1.0000x reference)
//
#include <hip/hip_runtime.h>
#include <math.h>

#define B_    16
#define N_    1024
#define G_    16      // blocks per batch
#define ITERS 100

// ws layout: [cnt: B_*ITERS u32, pad to 8192][mu_den: 4*B_*N_ f32][nug: B_*N_ f32]
#define MUDEN_OFF   8192
#define MUDEN_BYTES (4 * B_ * N_ * 4)
#define NUG_OFF     (MUDEN_OFF + MUDEN_BYTES)
#define ZERO_BYTES  NUG_OFF     // cnt + all 4 mu_den buffers start at 0

__device__ __forceinline__ float fast_div(float num, float den) {
    float r = __builtin_amdgcn_rcpf(den);
    r = r * (2.0f - den * r);      // one Newton step -> ~full fp32 accuracy
    return num * r;
}

// Full 64-lane wave sum via DPP (zero DS-pipe ops, pure VALU):
// row_shr:1/2/4/8 builds 16-lane row sums (lane 15 of each row), then
// row_bcast:15 + row_bcast:31 accumulate rows into lane 63. Lane 47 gets
// contaminated by the unmasked bcast15 add, but bcast31 reads only lane 31,
// so lane 63 is exact. Broadcast back wave-uniform via readlane(63).
__device__ __forceinline__ float wave_sum64(float x) {
#define DPP_ADD(ctrl)                                                   \
    x += __int_as_float(__builtin_amdgcn_update_dpp(                    \
            0, __float_as_int(x), ctrl, 0xf, 0xf, false));
    DPP_ADD(0x111)  // row_shr:1
    DPP_ADD(0x112)  // row_shr:2
    DPP_ADD(0x114)  // row_shr:4
    DPP_ADD(0x118)  // row_shr:8
    DPP_ADD(0x142)  // row_bcast:15
    DPP_ADD(0x143)  // row_bcast:31
#undef DPP_ADD
    return __int_as_float(__builtin_amdgcn_readlane(__float_as_int(x), 63));
}

// R5 structure (fence-free 4-buffer rotation, L2 f32-atomic exchange) with the
// LDS pipe decongested:
//   - Phase A reduce: DPP chain instead of __shfl_xor (24 DS ops -> 0)
//   - Phase B reduce: per-wave ds_add_f32 into one colacc[1024] accumulator
//     instead of 16 slabs + gather (32 DS ops -> ~18); reader self-re-zeroes
//     its own element after the read (no extra barrier needed).
// Ordering (validated R4/R5): __syncthreads() drains lgkmcnt+vmcnt per wave,
// so all ds_adds precede the S1 read, and global atomics are at the coherence
// point before tid 0's arrival add; readers load only after the poll observes
// all 16 arrivals.
__global__ __launch_bounds__(1024, 4)
void sinkhorn_kernel(const float* __restrict__ C, float* __restrict__ out,
                     float* __restrict__ mu_den, float* __restrict__ nug,
                     unsigned int* __restrict__ cnt)
{
    __shared__ float colacc[N_];        // 4 KB: cross-wave column accumulator
    __shared__ float mu_s[N_];          // 4 KB: current mu

    const int tid = threadIdx.x;
    const int w   = tid >> 6;        // wave 0..15 -> 4-row group
    const int l   = tid & 63;
    // XCD-affinity swizzle: batch b's 16 blocks share bid%8 -> same XCD L2
    const int bid = blockIdx.x;
    const int xx = bid & 7, ss = bid >> 3;
    const int b = xx + ((ss >> 4) << 3);
    const int g = ss & 15;
    const int row0 = 64 * g + 4 * w;
    const float cons = 1.0f / 1024.0f;

    // ---- one-time: U tile = exp(-C/eps) into registers ----
    float u[4][16];
    {
        const float* Cb = C + (size_t)b * N_ * N_ + (size_t)row0 * N_ + l;
        #pragma unroll
        for (int rr = 0; rr < 4; ++rr)
            #pragma unroll
            for (int q = 0; q < 16; ++q)
                u[rr][q] = expf(-20.0f * Cb[(size_t)rr * N_ + 64 * q]);
    }

    mu_s[tid]   = cons;
    colacc[tid] = 0.0f;
    __syncthreads();

    for (int it = 0; it < ITERS; ++it) {
        // ---- Phase A: s_i = sum_j U_ij * mu_j (conflict-free LDS reads) ----
        float a0 = 0.f, a1 = 0.f, a2 = 0.f, a3 = 0.f;
        #pragma unroll
        for (int q = 0; q < 16; ++q) {
            float m = mu_s[l + 64 * q];
            a0 += u[0][q] * m;
            a1 += u[1][q] * m;
            a2 += u[2][q] * m;
            a3 += u[3][q] * m;
        }
        a0 = wave_sum64(a0);
        a1 = wave_sum64(a1);
        a2 = wave_sum64(a2);
        a3 = wave_sum64(a3);
        float nu0 = fast_div(cons, a0);
        float nu1 = fast_div(cons, a1);
        float nu2 = fast_div(cons, a2);
        float nu3 = fast_div(cons, a3);

        if (it == ITERS - 1 && l < 4) {   // publish final nu chunk (coherent)
            float nv = (l == 0) ? nu0 : (l == 1) ? nu1 : (l == 2) ? nu2 : nu3;
            __hip_atomic_store(&nug[b * N_ + row0 + l], nv,
                               __ATOMIC_RELAXED, __HIP_MEMORY_SCOPE_AGENT);
        }

        // ---- Phase B: accumulate per-wave column partials into colacc ----
        // (no sync needed before this: colacc was re-zeroed before S2 of the
        //  previous iteration, and nothing reads it until S1 below)
        #pragma unroll
        for (int q = 0; q < 16; ++q) {
            float p = u[0][q]*nu0 + u[1][q]*nu1 + u[2][q]*nu2 + u[3][q]*nu3;
            unsafeAtomicAdd(&colacc[l + 64 * q], p);   // ds_add_f32
        }
        __syncthreads();   // S1: all waves' ds_adds complete

        // single owner per column: read, self-re-zero, push to L2 accumulator
        const int buf = it & 3;
        {
            float ssum = colacc[tid];
            colacc[tid] = 0.0f;     // only thread tid touches index tid here
            unsafeAtomicAdd(&mu_den[((size_t)buf * B_ + b) * N_ + tid], ssum);
        }

        // ---- fence-free device barrier among the 16 blocks of batch b ----
        __syncthreads();   // S2: each wave's vmcnt(0) -> adds at coherence pt
        if (tid == 0) {
            unsigned int* c = &cnt[b * ITERS + it];
            __hip_atomic_fetch_add(c, 1u, __ATOMIC_RELAXED, __HIP_MEMORY_SCOPE_AGENT);
            while (__hip_atomic_load(c, __ATOMIC_RELAXED, __HIP_MEMORY_SCOPE_AGENT) < G_)
                __builtin_amdgcn_s_sleep(1);
        }
        __syncthreads();   // S3

        // ---- single readback -> new mu; zero the buffer for iter it+2 ----
        {
            float den = __hip_atomic_load(&mu_den[((size_t)buf * B_ + b) * N_ + tid],
                                          __ATOMIC_RELAXED, __HIP_MEMORY_SCOPE_AGENT);
            mu_s[tid] = fast_div(cons, den);
        }
        if (tid < 64)   // my block's 1/16 share of the buffer reused at it+2
            __hip_atomic_store(&mu_den[((size_t)((it + 2) & 3) * B_ + b) * N_ + 64 * g + tid],
                               0.0f, __ATOMIC_RELAXED, __HIP_MEMORY_SCOPE_AGENT);
        __syncthreads();   // S4: mu_s ready for next phase A
    }

    // ---- epilogue: T_ij = mu_i * U_ij * nu_j ----
    float mu_i[4];
    #pragma unroll
    for (int rr = 0; rr < 4; ++rr)
        mu_i[rr] = mu_s[row0 + rr];          // broadcast read

    float* ob = out + (size_t)b * N_ * N_ + (size_t)row0 * N_ + l;
    #pragma unroll
    for (int q = 0; q < 16; ++q) {
        float nuv = __hip_atomic_load(&nug[b * N_ + l + 64 * q],
                                      __ATOMIC_RELAXED, __HIP_MEMORY_SCOPE_AGENT);
        #pragma unroll
        for (int rr = 0; rr < 4; ++rr)
            ob[(size_t)rr * N_ + 64 * q] = mu_i[rr] * u[rr][q] * nuv;
    }
}

extern "C" void kernel_launch(void* const* d_in, const int* in_sizes, int n_in,
                              void* d_out, int out_size, void* d_ws, size_t ws_size,
                              hipStream_t stream) {
    const float* C = (const float*)d_in[2];     // (B, N, N); x,y unused
    float* out = (float*)d_out;

    unsigned char* ws = (unsigned char*)d_ws;
    unsigned int* cnt = (unsigned int*)ws;
    float* mu_den = (float*)(ws + MUDEN_OFF);
    float* nug    = (float*)(ws + NUG_OFF);

    // cnt + mu_den buffers must start at zero (buffers 2,3 are re-zeroed
    // in-kernel during iters 0,1 as part of the rotation anyway)
    hipMemsetAsync(ws, 0, ZERO_BYTES, stream);
    hipLaunchKernelGGL(sinkhorn_kernel, dim3(256), dim3(1024), 0, stream,
                       C, out, mu_den, nug, cnt);
}

// Round 2
// 670.008 us; speedup vs baseline: 3.4807x; 3.4807x over previous
//
#include <hip/hip_runtime.h>
#include <math.h>

#define B_    16
#define N_    1024
#define G_    16      // blocks per batch
#define ITERS 100

// ws layout: [cnt: B_*ITERS u32, pad to 8192][mu_den: 4*B_*N_ f32][nug: B_*N_ f32]
#define MUDEN_OFF   8192
#define MUDEN_BYTES (4 * B_ * N_ * 4)
#define NUG_OFF     (MUDEN_OFF + MUDEN_BYTES)
#define ZERO_BYTES  NUG_OFF     // cnt + all 4 mu_den buffers start at 0

__device__ __forceinline__ float fast_div(float num, float den) {
    float r = __builtin_amdgcn_rcpf(den);
    r = r * (2.0f - den * r);      // one Newton step -> ~full fp32 accuracy
    return num * r;
}

// Full 64-lane wave sum via DPP (zero DS-pipe ops, pure VALU). Proven correct
// in R1 (passed, absmax 1.19e-7). row_shr:1/2/4/8 builds 16-lane row sums in
// lane 15 of each row; row_bcast:15 + row_bcast:31 fold rows into lane 63.
__device__ __forceinline__ float wave_sum64(float x) {
#define DPP_ADD(ctrl)                                                   \
    x += __int_as_float(__builtin_amdgcn_update_dpp(                    \
            0, __float_as_int(x), ctrl, 0xf, 0xf, false));
    DPP_ADD(0x111)  // row_shr:1
    DPP_ADD(0x112)  // row_shr:2
    DPP_ADD(0x114)  // row_shr:4
    DPP_ADD(0x118)  // row_shr:8
    DPP_ADD(0x142)  // row_bcast:15
    DPP_ADD(0x143)  // row_bcast:31
#undef DPP_ADD
    return __int_as_float(__builtin_amdgcn_readlane(__float_as_int(x), 63));
}

// R7: R5's proven fence-free structure (slab + gather, NO LDS atomics --
// R6's unsafeAtomicAdd-on-LDS lowered to flat atomics, 6x regression).
// Changes vs R5:
//   - Phase A reduce: DPP chain (24 DS ops -> 0 VALU-pipe, proven R6)
//   - Column remap col = 4*l + s + 256*ch: every hot LDS access becomes a
//     conflict-free b128 op (phase A 16 b32 -> 4 b128 reads; slab 16 b32 ->
//     4 b128 writes; gather 256 wave-instr b32 -> 64 wave-instr b128 by
//     waves 0-3). U loads + epilogue stores become coalesced float4.
// Ordering (validated R4/R5): __syncthreads() drains vmcnt per wave before
// s_barrier, so global atomics are at the L2 coherence point before tid 0's
// arrival add; readers use sc0 atomic loads only after the poll observes all
// 16 arrivals (plain loads could hit stale L1).
__global__ __launch_bounds__(1024, 4)
void sinkhorn_kernel(const float* __restrict__ C, float* __restrict__ out,
                     float* __restrict__ mu_den, float* __restrict__ nug,
                     unsigned int* __restrict__ cnt)
{
    __shared__ float part[16 * 1024];   // 64 KB: per-wave column-partial slabs
    __shared__ float mu_s[N_];          // 4 KB: current mu

    const int tid = threadIdx.x;
    const int w   = tid >> 6;        // wave 0..15 -> 4-row group
    const int l   = tid & 63;
    // XCD-affinity swizzle: batch b's 16 blocks share bid%8 -> same XCD L2
    const int bid = blockIdx.x;
    const int xx = bid & 7, ss = bid >> 3;
    const int b = xx + ((ss >> 4) << 3);
    const int g = ss & 15;
    const int row0 = 64 * g + 4 * w;
    const float cons = 1.0f / 1024.0f;

    // ---- one-time: U tile = exp(-C/eps), columns 4*l + s + 256*ch ----
    float u[4][16];
    {
        const float* Cb = C + (size_t)b * N_ * N_ + (size_t)row0 * N_;
        #pragma unroll
        for (int rr = 0; rr < 4; ++rr)
            #pragma unroll
            for (int ch = 0; ch < 4; ++ch) {
                float4 cv = *(const float4*)(Cb + (size_t)rr * N_ + 4 * l + 256 * ch);
                u[rr][4*ch+0] = expf(-20.0f * cv.x);
                u[rr][4*ch+1] = expf(-20.0f * cv.y);
                u[rr][4*ch+2] = expf(-20.0f * cv.z);
                u[rr][4*ch+3] = expf(-20.0f * cv.w);
            }
    }

    mu_s[tid] = cons;
    __syncthreads();

    for (int it = 0; it < ITERS; ++it) {
        // ---- Phase A: s_i = sum_j U_ij * mu_j (4x ds_read_b128) ----
        float a0 = 0.f, a1 = 0.f, a2 = 0.f, a3 = 0.f;
        #pragma unroll
        for (int ch = 0; ch < 4; ++ch) {
            float4 mv = *(const float4*)&mu_s[4 * l + 256 * ch];
            a0 += u[0][4*ch+0]*mv.x + u[0][4*ch+1]*mv.y + u[0][4*ch+2]*mv.z + u[0][4*ch+3]*mv.w;
            a1 += u[1][4*ch+0]*mv.x + u[1][4*ch+1]*mv.y + u[1][4*ch+2]*mv.z + u[1][4*ch+3]*mv.w;
            a2 += u[2][4*ch+0]*mv.x + u[2][4*ch+1]*mv.y + u[2][4*ch+2]*mv.z + u[2][4*ch+3]*mv.w;
            a3 += u[3][4*ch+0]*mv.x + u[3][4*ch+1]*mv.y + u[3][4*ch+2]*mv.z + u[3][4*ch+3]*mv.w;
        }
        a0 = wave_sum64(a0);
        a1 = wave_sum64(a1);
        a2 = wave_sum64(a2);
        a3 = wave_sum64(a3);
        float nu0 = fast_div(cons, a0);
        float nu1 = fast_div(cons, a1);
        float nu2 = fast_div(cons, a2);
        float nu3 = fast_div(cons, a3);

        if (it == ITERS - 1 && l < 4) {   // publish final nu chunk (coherent)
            float nv = (l == 0) ? nu0 : (l == 1) ? nu1 : (l == 2) ? nu2 : nu3;
            __hip_atomic_store(&nug[b * N_ + row0 + l], nv,
                               __ATOMIC_RELAXED, __HIP_MEMORY_SCOPE_AGENT);
        }

        // ---- Phase B: per-wave column partials -> slab (4x ds_write_b128) ----
        // (no sync needed before this: iter it-1's gather reads finished
        //  before S2 of it-1 < here; part[] and mu_s[] are separate arrays)
        #pragma unroll
        for (int ch = 0; ch < 4; ++ch) {
            float4 p;
            p.x = u[0][4*ch+0]*nu0 + u[1][4*ch+0]*nu1 + u[2][4*ch+0]*nu2 + u[3][4*ch+0]*nu3;
            p.y = u[0][4*ch+1]*nu0 + u[1][4*ch+1]*nu1 + u[2][4*ch+1]*nu2 + u[3][4*ch+1]*nu3;
            p.z = u[0][4*ch+2]*nu0 + u[1][4*ch+2]*nu1 + u[2][4*ch+2]*nu2 + u[3][4*ch+2]*nu3;
            p.w = u[0][4*ch+3]*nu0 + u[1][4*ch+3]*nu1 + u[2][4*ch+3]*nu2 + u[3][4*ch+3]*nu3;
            *(float4*)&part[w * 1024 + 4 * l + 256 * ch] = p;
        }
        __syncthreads();   // S1: slabs complete

        // column sums across 16 slabs: waves 0-3, float4 per thread
        // (64 b128 wave-instrs instead of 256 b32), then 4 L2 f32 atomics
        const int buf = it & 3;
        if (tid < 256) {
            float4 s4 = {0.f, 0.f, 0.f, 0.f};
            #pragma unroll
            for (int w2 = 0; w2 < 16; ++w2) {
                float4 v = *(const float4*)&part[w2 * 1024 + 4 * tid];
                s4.x += v.x; s4.y += v.y; s4.z += v.z; s4.w += v.w;
            }
            float* md = &mu_den[((size_t)buf * B_ + b) * N_ + 4 * tid];
            unsafeAtomicAdd(md + 0, s4.x);      // global f32 atomics (L2)
            unsafeAtomicAdd(md + 1, s4.y);
            unsafeAtomicAdd(md + 2, s4.z);
            unsafeAtomicAdd(md + 3, s4.w);
        }

        // ---- fence-free device barrier among the 16 blocks of batch b ----
        __syncthreads();   // S2: each wave's vmcnt(0) -> adds at coherence pt
        if (tid == 0) {
            unsigned int* c = &cnt[b * ITERS + it];
            __hip_atomic_fetch_add(c, 1u, __ATOMIC_RELAXED, __HIP_MEMORY_SCOPE_AGENT);
            while (__hip_atomic_load(c, __ATOMIC_RELAXED, __HIP_MEMORY_SCOPE_AGENT) < G_)
                __builtin_amdgcn_s_sleep(1);
        }
        __syncthreads();   // S3

        // ---- single readback -> new mu; zero the buffer for iter it+2 ----
        {
            float den = __hip_atomic_load(&mu_den[((size_t)buf * B_ + b) * N_ + tid],
                                          __ATOMIC_RELAXED, __HIP_MEMORY_SCOPE_AGENT);
            mu_s[tid] = fast_div(cons, den);
        }
        if (tid < 64)   // my block's 1/16 share of the buffer reused at it+2
            __hip_atomic_store(&mu_den[((size_t)((it + 2) & 3) * B_ + b) * N_ + 64 * g + tid],
                               0.0f, __ATOMIC_RELAXED, __HIP_MEMORY_SCOPE_AGENT);
        __syncthreads();   // S4: mu_s ready for next phase A
    }

    // ---- epilogue: T_ij = mu_i * U_ij * nu_j (float4 stores) ----
    float mu_i[4];
    #pragma unroll
    for (int rr = 0; rr < 4; ++rr)
        mu_i[rr] = mu_s[row0 + rr];          // broadcast read

    float* ob = out + (size_t)b * N_ * N_ + (size_t)row0 * N_;
    #pragma unroll
    for (int ch = 0; ch < 4; ++ch) {
        const int cbase = b * N_ + 4 * l + 256 * ch;
        float4 nuv;
        nuv.x = __hip_atomic_load(&nug[cbase + 0], __ATOMIC_RELAXED, __HIP_MEMORY_SCOPE_AGENT);
        nuv.y = __hip_atomic_load(&nug[cbase + 1], __ATOMIC_RELAXED, __HIP_MEMORY_SCOPE_AGENT);
        nuv.z = __hip_atomic_load(&nug[cbase + 2], __ATOMIC_RELAXED, __HIP_MEMORY_SCOPE_AGENT);
        nuv.w = __hip_atomic_load(&nug[cbase + 3], __ATOMIC_RELAXED, __HIP_MEMORY_SCOPE_AGENT);
        #pragma unroll
        for (int rr = 0; rr < 4; ++rr) {
            float4 t;
            t.x = mu_i[rr] * u[rr][4*ch+0] * nuv.x;
            t.y = mu_i[rr] * u[rr][4*ch+1] * nuv.y;
            t.z = mu_i[rr] * u[rr][4*ch+2] * nuv.z;
            t.w = mu_i[rr] * u[rr][4*ch+3] * nuv.w;
            *(float4*)(ob + (size_t)rr * N_ + 4 * l + 256 * ch) = t;
        }
    }
}

extern "C" void kernel_launch(void* const* d_in, const int* in_sizes, int n_in,
                              void* d_out, int out_size, void* d_ws, size_t ws_size,
                              hipStream_t stream) {
    const float* C = (const float*)d_in[2];     // (B, N, N); x,y unused
    float* out = (float*)d_out;

    unsigned char* ws = (unsigned char*)d_ws;
    unsigned int* cnt = (unsigned int*)ws;
    float* mu_den = (float*)(ws + MUDEN_OFF);
    float* nug    = (float*)(ws + NUG_OFF);

    // cnt + mu_den buffers must start at zero (buffers 2,3 are re-zeroed
    // in-kernel during iters 0,1 as part of the rotation anyway)
    hipMemsetAsync(ws, 0, ZERO_BYTES, stream);
    hipLaunchKernelGGL(sinkhorn_kernel, dim3(256), dim3(1024), 0, stream,
                       C, out, mu_den, nug, cnt);
}

// Round 3
// 398.821 us; speedup vs baseline: 5.8474x; 1.6800x over previous
//
#include <hip/hip_runtime.h>
#include <math.h>

#define B_    16
#define N_    1024
#define G_    16      // blocks per batch
#define ITERS 100

// ws layout: [cnt: B_*ITERS u32, pad to 8192][mu_den: 4*B_*N_ f32][nug: B_*N_ f32]
#define MUDEN_OFF   8192
#define MUDEN_BYTES (4 * B_ * N_ * 4)
#define NUG_OFF     (MUDEN_OFF + MUDEN_BYTES)
#define ZERO_BYTES  NUG_OFF     // cnt + all 4 mu_den buffers start at 0

__device__ __forceinline__ float fast_div(float num, float den) {
    float r = __builtin_amdgcn_rcpf(den);
    r = r * (2.0f - den * r);      // one Newton step -> ~full fp32 accuracy
    return num * r;
}

// Full 64-lane wave sum via DPP (zero DS-pipe ops, pure VALU). Proven correct
// R1/R2 (passed, absmax 1.19e-7). row_shr:1/2/4/8 builds 16-lane row sums in
// lane 15 of each row; row_bcast:15 + row_bcast:31 fold rows into lane 63.
__device__ __forceinline__ float wave_sum64(float x) {
#define DPP_ADD(ctrl)                                                   \
    x += __int_as_float(__builtin_amdgcn_update_dpp(                    \
            0, __float_as_int(x), ctrl, 0xf, 0xf, false));
    DPP_ADD(0x111)  // row_shr:1
    DPP_ADD(0x112)  // row_shr:2
    DPP_ADD(0x114)  // row_shr:4
    DPP_ADD(0x118)  // row_shr:8
    DPP_ADD(0x142)  // row_bcast:15
    DPP_ADD(0x143)  // row_bcast:31
#undef DPP_ADD
    return __int_as_float(__builtin_amdgcn_readlane(__float_as_int(x), 63));
}

// R8 = R7 with the exchange atomics reverted to baseline's CONTIGUOUS pattern.
// R7 lesson (WRITE_SIZE 175MB -> 502MB): global atomic adds at lane-stride
// 16B span 16 cache lines per wave-instr -> 4x HBM write amplification.
// Baseline pattern (thread tid -> address tid, one atomic) keeps each wave's
// 64 atomics inside 4 whole lines. Kept from R7:
//   - Phase A: 4x ds_read_b128 mu reads + DPP reduce (no DS-pipe shuffles)
//   - Phase B: 4x ds_write_b128 slab writes (column remap col=4l+s+256ch)
//   - float4 U-tile loads, float4 epilogue stores
// Ordering (validated R4/R5): __syncthreads() drains vmcnt per wave before
// s_barrier, so atomics are at the L2 coherence point before tid 0's arrival
// add; readers use coherent atomic loads only after the poll sees 16 arrivals.
__global__ __launch_bounds__(1024, 4)
void sinkhorn_kernel(const float* __restrict__ C, float* __restrict__ out,
                     float* __restrict__ mu_den, float* __restrict__ nug,
                     unsigned int* __restrict__ cnt)
{
    __shared__ float part[16 * 1024];   // 64 KB: per-wave column-partial slabs
    __shared__ float mu_s[N_];          // 4 KB: current mu

    const int tid = threadIdx.x;
    const int w   = tid >> 6;        // wave 0..15 -> 4-row group
    const int l   = tid & 63;
    // XCD-affinity swizzle: batch b's 16 blocks share bid%8 -> same XCD L2
    const int bid = blockIdx.x;
    const int xx = bid & 7, ss = bid >> 3;
    const int b = xx + ((ss >> 4) << 3);
    const int g = ss & 15;
    const int row0 = 64 * g + 4 * w;
    const float cons = 1.0f / 1024.0f;

    // ---- one-time: U tile = exp(-C/eps), columns 4*l + s + 256*ch ----
    float u[4][16];
    {
        const float* Cb = C + (size_t)b * N_ * N_ + (size_t)row0 * N_;
        #pragma unroll
        for (int rr = 0; rr < 4; ++rr)
            #pragma unroll
            for (int ch = 0; ch < 4; ++ch) {
                float4 cv = *(const float4*)(Cb + (size_t)rr * N_ + 4 * l + 256 * ch);
                u[rr][4*ch+0] = expf(-20.0f * cv.x);
                u[rr][4*ch+1] = expf(-20.0f * cv.y);
                u[rr][4*ch+2] = expf(-20.0f * cv.z);
                u[rr][4*ch+3] = expf(-20.0f * cv.w);
            }
    }

    mu_s[tid] = cons;
    __syncthreads();

    for (int it = 0; it < ITERS; ++it) {
        // ---- Phase A: s_i = sum_j U_ij * mu_j (4x ds_read_b128) ----
        float a0 = 0.f, a1 = 0.f, a2 = 0.f, a3 = 0.f;
        #pragma unroll
        for (int ch = 0; ch < 4; ++ch) {
            float4 mv = *(const float4*)&mu_s[4 * l + 256 * ch];
            a0 += u[0][4*ch+0]*mv.x + u[0][4*ch+1]*mv.y + u[0][4*ch+2]*mv.z + u[0][4*ch+3]*mv.w;
            a1 += u[1][4*ch+0]*mv.x + u[1][4*ch+1]*mv.y + u[1][4*ch+2]*mv.z + u[1][4*ch+3]*mv.w;
            a2 += u[2][4*ch+0]*mv.x + u[2][4*ch+1]*mv.y + u[2][4*ch+2]*mv.z + u[2][4*ch+3]*mv.w;
            a3 += u[3][4*ch+0]*mv.x + u[3][4*ch+1]*mv.y + u[3][4*ch+2]*mv.z + u[3][4*ch+3]*mv.w;
        }
        a0 = wave_sum64(a0);
        a1 = wave_sum64(a1);
        a2 = wave_sum64(a2);
        a3 = wave_sum64(a3);
        float nu0 = fast_div(cons, a0);
        float nu1 = fast_div(cons, a1);
        float nu2 = fast_div(cons, a2);
        float nu3 = fast_div(cons, a3);

        if (it == ITERS - 1 && l < 4) {   // publish final nu chunk (coherent)
            float nv = (l == 0) ? nu0 : (l == 1) ? nu1 : (l == 2) ? nu2 : nu3;
            __hip_atomic_store(&nug[b * N_ + row0 + l], nv,
                               __ATOMIC_RELAXED, __HIP_MEMORY_SCOPE_AGENT);
        }

        // ---- Phase B: per-wave column partials -> slab (4x ds_write_b128) ----
        // (no sync needed before this: iter it-1's gather reads finished
        //  before S2 of it-1 < here; part[] and mu_s[] are separate arrays)
        #pragma unroll
        for (int ch = 0; ch < 4; ++ch) {
            float4 p;
            p.x = u[0][4*ch+0]*nu0 + u[1][4*ch+0]*nu1 + u[2][4*ch+0]*nu2 + u[3][4*ch+0]*nu3;
            p.y = u[0][4*ch+1]*nu0 + u[1][4*ch+1]*nu1 + u[2][4*ch+1]*nu2 + u[3][4*ch+1]*nu3;
            p.z = u[0][4*ch+2]*nu0 + u[1][4*ch+2]*nu1 + u[2][4*ch+2]*nu2 + u[3][4*ch+2]*nu3;
            p.w = u[0][4*ch+3]*nu0 + u[1][4*ch+3]*nu1 + u[2][4*ch+3]*nu2 + u[3][4*ch+3]*nu3;
            *(float4*)&part[w * 1024 + 4 * l + 256 * ch] = p;
        }
        __syncthreads();   // S1: slabs complete

        // column sums across 16 slabs; ONE contiguous f32 atomic per thread
        // (baseline-proven: wave's 64 atomics cover 4 whole cache lines)
        const int buf = it & 3;
        {
            float ssum = 0.f;
            #pragma unroll
            for (int w2 = 0; w2 < 16; ++w2)
                ssum += part[w2 * 1024 + tid];      // conflict-free b32
            unsafeAtomicAdd(&mu_den[((size_t)buf * B_ + b) * N_ + tid], ssum);
        }

        // ---- fence-free device barrier among the 16 blocks of batch b ----
        __syncthreads();   // S2: each wave's vmcnt(0) -> adds at coherence pt
        if (tid == 0) {
            unsigned int* c = &cnt[b * ITERS + it];
            __hip_atomic_fetch_add(c, 1u, __ATOMIC_RELAXED, __HIP_MEMORY_SCOPE_AGENT);
            while (__hip_atomic_load(c, __ATOMIC_RELAXED, __HIP_MEMORY_SCOPE_AGENT) < G_)
                __builtin_amdgcn_s_sleep(1);
        }
        __syncthreads();   // S3

        // ---- single readback -> new mu; zero the buffer for iter it+2 ----
        {
            float den = __hip_atomic_load(&mu_den[((size_t)buf * B_ + b) * N_ + tid],
                                          __ATOMIC_RELAXED, __HIP_MEMORY_SCOPE_AGENT);
            mu_s[tid] = fast_div(cons, den);
        }
        if (tid < 64)   // my block's 1/16 share of the buffer reused at it+2
            __hip_atomic_store(&mu_den[((size_t)((it + 2) & 3) * B_ + b) * N_ + 64 * g + tid],
                               0.0f, __ATOMIC_RELAXED, __HIP_MEMORY_SCOPE_AGENT);
        __syncthreads();   // S4: mu_s ready for next phase A
    }

    // ---- epilogue: T_ij = mu_i * U_ij * nu_j (float4 stores) ----
    float mu_i[4];
    #pragma unroll
    for (int rr = 0; rr < 4; ++rr)
        mu_i[rr] = mu_s[row0 + rr];          // broadcast read

    float* ob = out + (size_t)b * N_ * N_ + (size_t)row0 * N_;
    #pragma unroll
    for (int ch = 0; ch < 4; ++ch) {
        const int cbase = b * N_ + 4 * l + 256 * ch;
        float4 nuv;
        nuv.x = __hip_atomic_load(&nug[cbase + 0], __ATOMIC_RELAXED, __HIP_MEMORY_SCOPE_AGENT);
        nuv.y = __hip_atomic_load(&nug[cbase + 1], __ATOMIC_RELAXED, __HIP_MEMORY_SCOPE_AGENT);
        nuv.z = __hip_atomic_load(&nug[cbase + 2], __ATOMIC_RELAXED, __HIP_MEMORY_SCOPE_AGENT);
        nuv.w = __hip_atomic_load(&nug[cbase + 3], __ATOMIC_RELAXED, __HIP_MEMORY_SCOPE_AGENT);
        #pragma unroll
        for (int rr = 0; rr < 4; ++rr) {
            float4 t;
            t.x = mu_i[rr] * u[rr][4*ch+0] * nuv.x;
            t.y = mu_i[rr] * u[rr][4*ch+1] * nuv.y;
            t.z = mu_i[rr] * u[rr][4*ch+2] * nuv.z;
            t.w = mu_i[rr] * u[rr][4*ch+3] * nuv.w;
            *(float4*)(ob + (size_t)rr * N_ + 4 * l + 256 * ch) = t;
        }
    }
}

extern "C" void kernel_launch(void* const* d_in, const int* in_sizes, int n_in,
                              void* d_out, int out_size, void* d_ws, size_t ws_size,
                              hipStream_t stream) {
    const float* C = (const float*)d_in[2];     // (B, N, N); x,y unused
    float* out = (float*)d_out;

    unsigned char* ws = (unsigned char*)d_ws;
    unsigned int* cnt = (unsigned int*)ws;
    float* mu_den = (float*)(ws + MUDEN_OFF);
    float* nug    = (float*)(ws + NUG_OFF);

    // cnt + mu_den buffers must start at zero (buffers 2,3 are re-zeroed
    // in-kernel during iters 0,1 as part of the rotation anyway)
    hipMemsetAsync(ws, 0, ZERO_BYTES, stream);
    hipLaunchKernelGGL(sinkhorn_kernel, dim3(256), dim3(1024), 0, stream,
                       C, out, mu_den, nug, cnt);
}